// Round 1
// baseline (233.614 us; speedup 1.0000x reference)
//
#include <hip/hip_runtime.h>

#define NROWS 8192
#define DDIM  1024           // elements per row (fp8: also bytes per row)
#define BM 128
#define BN 256
#define BKB 64               // K-bytes per tile iteration (halved for double-buffer)
#define NKT (DDIM / BKB)     // 16 K-steps per column tile
#define NSTRIPES 8
#define CT_PER_STRIPE 4      // 8192 / (256*8)
#define MARGIN_F 0.05f
#define FP8_SCALE 8.0f       // power of 2; sims are scaled by 64 in mining space

typedef __attribute__((ext_vector_type(8)))  int   int8v;
typedef __attribute__((ext_vector_type(4)))  int   int4v;
typedef __attribute__((ext_vector_type(16))) float floatx16;

__device__ __forceinline__ void g2lds16(const void* g, void* l) {
  __builtin_amdgcn_global_load_lds(
      (const __attribute__((address_space(1))) void*)g,
      (__attribute__((address_space(3))) void*)l, 16, 0, 0);
}

// prep: 2048 blocks x 256 threads; wave w handles row 4*blockIdx + w.
// Exact fp32 pos_sim, fp32 -> fp8(e4m3, x8) quantize, zero keys + out.
__global__ void prep_kernel(const float* __restrict__ x, const float* __restrict__ y,
                            unsigned int* __restrict__ xq, unsigned int* __restrict__ yq,
                            float* __restrict__ pos, unsigned int* __restrict__ keys,
                            float* __restrict__ out) {
  const int t = threadIdx.x;
  const int lane = t & 63, wave = t >> 6;
  const int row = blockIdx.x * 4 + wave;
  const float4* xr = (const float4*)(x + (size_t)row * DDIM);
  const float4* yr = (const float4*)(y + (size_t)row * DDIM);
  unsigned int* xqr = xq + (size_t)row * 256;
  unsigned int* yqr = yq + (size_t)row * 256;
  float s = 0.f;
#pragma unroll
  for (int u = 0; u < 4; ++u) {
    const float4 a = xr[u * 64 + lane];
    const float4 b = yr[u * 64 + lane];
    s += a.x * b.x + a.y * b.y + a.z * b.z + a.w * b.w;
    int pa = __builtin_amdgcn_cvt_pk_fp8_f32(a.x * FP8_SCALE, a.y * FP8_SCALE, 0, false);
    pa     = __builtin_amdgcn_cvt_pk_fp8_f32(a.z * FP8_SCALE, a.w * FP8_SCALE, pa, true);
    int pb = __builtin_amdgcn_cvt_pk_fp8_f32(b.x * FP8_SCALE, b.y * FP8_SCALE, 0, false);
    pb     = __builtin_amdgcn_cvt_pk_fp8_f32(b.z * FP8_SCALE, b.w * FP8_SCALE, pb, true);
    xqr[u * 64 + lane] = (unsigned int)pa;
    yqr[u * 64 + lane] = (unsigned int)pb;
  }
  for (int m = 32; m; m >>= 1) s += __shfl_down(s, m, 64);
  if (lane == 0) { pos[row] = s; keys[row] = 0u; }
  if (blockIdx.x == 0 && t == 0) out[0] = 0.f;
}

// R9: double-buffered LDS + prefetch-after-barrier (T3-lite, depth-1).
// Old structure: sync -> issue 12 gload_lds -> sync(vmcnt(0) drain!) -> compute.
// The drain serialized ~1750 cyc/K-step of L2->LDS staging with compute.
// New structure per K-step: sync (drain is pre-satisfied: the loads it waits
// on were issued one full compute phase ago) -> issue next tile into the
// OTHER buffer (safe: the barrier just retired all reads of it) -> compute.
// BKB halved to 64 so 2x(A 8K + B 16K) = 48 KB keeps 2 blocks/CU.
//
// LDS swizzle for 64-B rows (4x16B chunks): chunk c of row r stored at
// c ^ ((r>>1)&3). ds_read side: lane (r31,kh) reads chunks {2kh, 2kh+1} of
// row base+r31; bank group = 4*(r&1) + storedpos — uniform 8 lanes/group for
// both lo and hi b128 reads (conflict-minimal). Row bases (64wr, 32mi, 128wc,
// 32ni) are multiples of 32 so the swizzle term depends only on r31.
// Global side: 4 consecutive lanes cover one row's 64-B segment (permuted
// within) -> coalesced; the other half of each 128-B line is an L2 hit on
// the next K-step.
// Epilogue unchanged: per-ct VALU-only running 32-bit keys; single butterfly
// + atomicMax per row at kernel end.
__global__ __launch_bounds__(256, 2) void mine_kernel(
    const unsigned char* __restrict__ xq, const unsigned char* __restrict__ yq,
    const float* __restrict__ pos, unsigned int* __restrict__ keys) {
  __shared__ unsigned char As[2 * BM * BKB];  // 16 KB (2 x 8 KB), XOR-swizzled
  __shared__ unsigned char Bs[2 * BN * BKB];  // 32 KB (2 x 16 KB), XOR-swizzled
  __shared__ float pos_s[BM];

  const int t = threadIdx.x;
  const int rowBase = blockIdx.x * BM;
  const int stripe  = blockIdx.y;
  if (t < BM) pos_s[t] = pos[rowBase + t] * (FP8_SCALE * FP8_SCALE);

  const int lane = t & 63;
  const int wave = t >> 6;
  const int wr = wave >> 1, wc = wave & 1;
  const int r31 = lane & 31, kh = lane >> 5;

  const int fragOff = (((2 * kh) ^ ((r31 >> 1) & 3)) << 4);
  const int offA0 = (64 * wr + r31) * BKB + fragOff;   // + mi*32*BKB
  const int offB0 = (128 * wc + r31) * BKB + fragOff;  // + ni*32*BKB

  unsigned int key[2][16];
#pragma unroll
  for (int mi = 0; mi < 2; ++mi)
#pragma unroll
    for (int reg = 0; reg < 16; ++reg) key[mi][reg] = 0u;

  // Stage one 64-B-deep K-tile (A: 2 issues/thread, B: 4) into buffer db.
  // Dest is wave-uniform base + lane*16 (HW adds the lane offset); the
  // swizzle is carried entirely by the per-lane GLOBAL source address.
#define STAGE(nct, nkt, db)                                                    \
  do {                                                                         \
    const int k0_ = (nkt) * BKB;                                               \
    const int cb_ = stripe * (BN * CT_PER_STRIPE) + (nct) * BN;                \
    _Pragma("unroll")                                                          \
    for (int i_ = 0; i_ < 2; ++i_) {                                           \
      const int s_ = i_ * 256 + t;                                             \
      const int r_ = s_ >> 2;                                                  \
      const int c_ = (s_ & 3) ^ ((r_ >> 1) & 3);                               \
      g2lds16(xq + (size_t)(rowBase + r_) * DDIM + k0_ + c_ * 16,              \
              &As[(db) * (BM * BKB) + (i_ * 256 + wave * 64) * 16]);           \
    }                                                                          \
    _Pragma("unroll")                                                          \
    for (int i_ = 0; i_ < 4; ++i_) {                                           \
      const int s_ = i_ * 256 + t;                                             \
      const int r_ = s_ >> 2;                                                  \
      const int c_ = (s_ & 3) ^ ((r_ >> 1) & 3);                               \
      g2lds16(yq + (size_t)(cb_ + r_) * DDIM + k0_ + c_ * 16,                  \
              &Bs[(db) * (BN * BKB) + (i_ * 256 + wave * 64) * 16]);           \
    }                                                                          \
  } while (0)

  int db = 0;
  STAGE(0, 0, 0);  // prologue; first barrier drains it (once per block)

  for (int ct = 0; ct < CT_PER_STRIPE; ++ct) {
    const int colBase = stripe * (BN * CT_PER_STRIPE) + ct * BN;

    floatx16 acc[2][4];
#pragma unroll
    for (int mi = 0; mi < 2; ++mi)
#pragma unroll
      for (int ni = 0; ni < 4; ++ni)
#pragma unroll
        for (int r = 0; r < 16; ++r) acc[mi][ni][r] = 0.f;

    // NKT is even -> db returns to 0 at each ct boundary; unroll 2 keeps all
    // buffer indices compile-time constant.
#pragma unroll 2
    for (int kt = 0; kt < NKT; ++kt) {
      __syncthreads();  // pre-satisfied vmcnt drain + retires reads of db^1
      {
        int nct = ct, nkt = kt + 1;
        if (nkt == NKT) { nct = ct + 1; nkt = 0; }
        if (nct < CT_PER_STRIPE) STAGE(nct, nkt, db ^ 1);
      }
      const unsigned char* Ab = &As[db * (BM * BKB)];
      const unsigned char* Bb = &Bs[db * (BN * BKB)];
      int8v af[2];
#pragma unroll
      for (int mi = 0; mi < 2; ++mi) {
        const int oA = offA0 + mi * 32 * BKB;
        int4v lo = *(const int4v*)&Ab[oA];
        int4v hi = *(const int4v*)&Ab[oA ^ 16];
        af[mi] = __builtin_shufflevector(lo, hi, 0, 1, 2, 3, 4, 5, 6, 7);
      }
#pragma unroll
      for (int ni = 0; ni < 4; ++ni) {
        const int oB = offB0 + ni * 32 * BKB;
        int4v blo = *(const int4v*)&Bb[oB];
        int4v bhi = *(const int4v*)&Bb[oB ^ 16];
        int8v bf = __builtin_shufflevector(blo, bhi, 0, 1, 2, 3, 4, 5, 6, 7);
        acc[0][ni] = __builtin_amdgcn_mfma_scale_f32_32x32x64_f8f6f4(
            af[0], bf, acc[0][ni], 0, 0, 0, 0x7F7F7F7F, 0, 0x7F7F7F7F);
        acc[1][ni] = __builtin_amdgcn_mfma_scale_f32_32x32x64_f8f6f4(
            af[1], bf, acc[1][ni], 0, 0, 0, 0x7F7F7F7F, 0, 0x7F7F7F7F);
      }
      db ^= 1;
    }

    // Per-ct key update (pure VALU; overlaps the in-flight next-ct stage).
    // 32x32 C/D layout (HW-verified): col = lane&31,
    // row = (reg&3) + 8*(reg>>2) + 4*(lane>>5).
    int colv[4];
#pragma unroll
    for (int ni = 0; ni < 4; ++ni) colv[ni] = colBase + 128 * wc + 32 * ni + r31;
#pragma unroll
    for (int mi = 0; mi < 2; ++mi) {
#pragma unroll
      for (int reg = 0; reg < 16; ++reg) {
        const int row_l = 64 * wr + 32 * mi + (reg & 3) + 8 * (reg >> 2) + 4 * kh;
        const int row_g = rowBase + row_l;
        const float p = pos_s[row_l];
        unsigned int kk = key[mi][reg];
#pragma unroll
        for (int ni = 0; ni < 4; ++ni) {
          const float v = acc[mi][ni][reg];
          const bool dead = (colv[ni] == row_g) || (v > p);
          unsigned int u = __float_as_uint(v);
          u ^= (unsigned int)(((int)u) >> 31) | 0x80000000u;
          unsigned int kc = (u & 0xFFFFE000u) | (unsigned int)(8191 - colv[ni]);
          kc = dead ? 0u : kc;
          kk = kk > kc ? kk : kc;
        }
        key[mi][reg] = kk;
      }
    }
  }

  // One butterfly + one atomic per owned row.
#pragma unroll
  for (int mi = 0; mi < 2; ++mi) {
#pragma unroll
    for (int reg = 0; reg < 16; ++reg) {
      unsigned int kk = key[mi][reg];
#pragma unroll
      for (int m = 1; m <= 16; m <<= 1) {
        unsigned int o = __shfl_xor(kk, m, 64);
        kk = kk > o ? kk : o;
      }
      if (r31 == 0) {
        const int row_l = 64 * wr + 32 * mi + (reg & 3) + 8 * (reg >> 2) + 4 * kh;
        atomicMax(&keys[rowBase + row_l], kk);
      }
    }
  }
#undef STAGE
}

// Exact fp32 recompute of neg_sim for the mined index + loss reduction.
// R9: 1024 blocks (was 256) -> 4x wave parallelism for the latency-bound
// gather; 2 independent rows per wave keep ILP, 1024 total atomics on out.
__global__ void final_kernel(const float* __restrict__ x, const float* __restrict__ y,
                             const float* __restrict__ pos,
                             const unsigned int* __restrict__ keys,
                             float* __restrict__ out) {
  const int t = threadIdx.x;
  const int lane = t & 63, wave = t >> 6;
  float accl = 0.f;
#pragma unroll
  for (int i = 0; i < 2; ++i) {
    const int row = blockIdx.x * 8 + i * 4 + wave;
    const unsigned int k = keys[row];
    const int j = (k == 0u) ? 0 : (8191 - (int)(k & 8191u));  // all-masked -> argmax 0
    const float4* xr = (const float4*)(x + (size_t)row * DDIM);
    const float4* yr = (const float4*)(y + (size_t)j * DDIM);
    float s = 0.f;
#pragma unroll
    for (int u = 0; u < 4; ++u) {
      const float4 a = xr[lane + 64 * u];
      const float4 b = yr[lane + 64 * u];
      s += a.x * b.x + a.y * b.y + a.z * b.z + a.w * b.w;
    }
    for (int m = 32; m; m >>= 1) s += __shfl_down(s, m, 64);
    if (lane == 0) {
      const float l = MARGIN_F - pos[row] + s;
      accl += l > 0.f ? l : 0.f;
    }
  }
  __shared__ float ps[4];
  if (lane == 0) ps[wave] = accl;
  __syncthreads();
  if (t == 0) atomicAdd(out, (ps[0] + ps[1] + ps[2] + ps[3]) * (1.0f / (float)NROWS));
}

extern "C" void kernel_launch(void* const* d_in, const int* in_sizes, int n_in,
                              void* d_out, int out_size, void* d_ws, size_t ws_size,
                              hipStream_t stream) {
  const float* x = (const float*)d_in[0];
  const float* y = (const float*)d_in[1];
  float* out = (float*)d_out;

  // ws layout: keys 32 KB | pos 32 KB | xq 8 MB | yq 8 MB
  unsigned int* keys = (unsigned int*)d_ws;
  float* pos = (float*)((char*)d_ws + (size_t)NROWS * 4);
  unsigned char* xq = (unsigned char*)d_ws + (size_t)NROWS * 8;
  unsigned char* yq = xq + (size_t)NROWS * DDIM;

  prep_kernel<<<NROWS / 4, 256, 0, stream>>>(x, y, (unsigned int*)xq, (unsigned int*)yq,
                                             pos, keys, out);
  dim3 grid(NROWS / BM, NSTRIPES);
  mine_kernel<<<grid, 256, 0, stream>>>(xq, yq, pos, keys);
  final_kernel<<<NROWS / 8, 256, 0, stream>>>(x, y, pos, keys, out);
}